// Round 1
// baseline (103.616 us; speedup 1.0000x reference)
//
#include <hip/hip_runtime.h>

// ---------------------------------------------------------------------------
// Problem: DWT autoencoder round trip.
// Reduction: level-2 dwt2+idwt2 is an exact inverse pair -> LL1r == LL1.
// Remaining pipeline:
//   K1: haar dwt level1 of x -> LL1 (B,3,256,256)  +  conv3x3 s2 of the
//       9 detail bands -> y (B,9,128,128)
//   K2: convT4x4 s2 of y -> l1 bands, fused with idwt2(LL1, l1) -> out
// B=32, C=3, H=W=512.
// ---------------------------------------------------------------------------

#define BB 32

// K1: one block = one batch image, one 16x16 tile of y (128-res).
// Computes level1 bands for the 33x33 halo region (256-res) into LDS,
// writes the LL1 interior (32x32) to global, then the 9-channel 3x3 s2 conv.
__global__ __launch_bounds__(256) void k1_dwt_down(
    const float* __restrict__ x,     // (B,3,512,512)
    const float* __restrict__ dw,    // (9,9,3,3) OIHW
    const float* __restrict__ db,    // (9)
    float* __restrict__ LL1,         // (B,3,256,256)
    float* __restrict__ y)           // (B,9,128,128)
{
    __shared__ float lvl[9][33][33];   // [c*3+band][row][col], band: LH,HL,HH

    const int t    = threadIdx.x;
    const int b    = blockIdx.x >> 6;
    const int tile = blockIdx.x & 63;
    const int i0   = (tile >> 3) << 4;   // y tile origin (128-res)
    const int j0   = (tile & 7) << 4;
    const int gr0  = 2 * i0 - 1;         // level1 row of local row 0
    const int gc0  = 2 * j0 - 1;

    // ---- stage 1: DWT level 1 into LDS (+ LL1 interior to global) ----
    for (int item = t; item < 3 * 1089; item += 256) {
        const int ch  = item / 1089;
        int rem       = item - ch * 1089;
        const int lr  = rem / 33;
        const int lc  = rem - lr * 33;
        const int r   = gr0 + lr;        // level1 row in [-1, 255]
        const int c   = gc0 + lc;
        float x00 = 0.f, x01 = 0.f, x10 = 0.f, x11 = 0.f;
        if (r >= 0 && c >= 0 && r < 256 && c < 256) {
            const float* xp = x + (((size_t)b * 3 + ch) * 512 + 2 * r) * 512 + 2 * c;
            const float2 v0 = *reinterpret_cast<const float2*>(xp);
            const float2 v1 = *reinterpret_cast<const float2*>(xp + 512);
            x00 = v0.x; x01 = v0.y; x10 = v1.x; x11 = v1.y;
        }
        const float s0 = x00 + x01, d0 = x00 - x01;
        const float s1 = x10 + x11, d1 = x10 - x11;
        lvl[ch * 3 + 0][lr][lc] = (s0 - s1) * 0.5f;  // LH
        lvl[ch * 3 + 1][lr][lc] = (d0 + d1) * 0.5f;  // HL
        lvl[ch * 3 + 2][lr][lc] = (d0 - d1) * 0.5f;  // HH
        if (lr >= 1 && lc >= 1) {
            LL1[(((size_t)b * 3 + ch) * 256 + r) * 256 + c] = (s0 + s1) * 0.5f;
        }
    }
    __syncthreads();

    // ---- stage 2: 3x3 stride-2 conv, 9 in ch -> 9 out ch ----
    const int ti = t >> 4;   // 0..15
    const int tj = t & 15;
    float acc[9];
#pragma unroll
    for (int o = 0; o < 9; ++o) acc[o] = db[o];

    for (int cin = 0; cin < 9; ++cin) {
        float v[3][3];
#pragma unroll
        for (int a = 0; a < 3; ++a)
#pragma unroll
            for (int q = 0; q < 3; ++q)
                v[a][q] = lvl[cin][2 * ti + a][2 * tj + q];
#pragma unroll
        for (int a = 0; a < 3; ++a)
#pragma unroll
            for (int q = 0; q < 3; ++q) {
                const float vv = v[a][q];
#pragma unroll
                for (int o = 0; o < 9; ++o)
                    acc[o] += vv * dw[o * 81 + cin * 9 + a * 3 + q];  // uniform -> s_load
            }
    }
#pragma unroll
    for (int o = 0; o < 9; ++o)
        y[(((size_t)b * 9 + o) * 128 + (i0 + ti)) * 128 + (j0 + tj)] = acc[o];
}

// K2: one block = one batch image, a 32x32 tile at 256-res (=> 64x64 output
// pixels at 512-res) for all 3 colors. Each thread owns a 2x2 "quad block"
// so convT tap indices are compile-time -> uniform weight loads.
__global__ __launch_bounds__(256) void k2_up_idwt(
    const float* __restrict__ yg,    // (B,9,128,128)
    const float* __restrict__ uw,    // (9,9,4,4)  (in,out,kh,kw)
    const float* __restrict__ ub,    // (9)
    const float* __restrict__ LL1,   // (B,3,256,256)
    float* __restrict__ out)         // (B,3,512,512)
{
    __shared__ float ysh[9][18][19];

    const int t    = threadIdx.x;
    const int b    = blockIdx.x >> 6;
    const int tile = blockIdx.x & 63;
    const int r0   = (tile >> 3) << 5;  // 256-res tile origin
    const int c0   = (tile & 7) << 5;
    const int p0   = (r0 >> 1) - 1;     // y row of local 0
    const int q0   = (c0 >> 1) - 1;

    // ---- stage y tile (18x18 halo, 9 ch) into LDS ----
    for (int item = t; item < 9 * 324; item += 256) {
        const int cin = item / 324;
        int rem       = item - cin * 324;
        const int lp  = rem / 18;
        const int lq  = rem - lp * 18;
        const int p   = p0 + lp, q = q0 + lq;
        float v = 0.f;
        if (p >= 0 && p < 128 && q >= 0 && q < 128)
            v = yg[(((size_t)b * 9 + cin) * 128 + p) * 128 + q];
        ysh[cin][lp][lq] = v;
    }
    __syncthreads();

    const int i2 = t >> 4;   // quad-block coords, 16x16
    const int j2 = t & 15;

    float acc[2][2][9];      // [di][dj][out-ch]
#pragma unroll
    for (int di = 0; di < 2; ++di)
#pragma unroll
        for (int dj = 0; dj < 2; ++dj)
#pragma unroll
            for (int o = 0; o < 9; ++o) acc[di][dj][o] = ub[o];

    for (int cin = 0; cin < 9; ++cin) {
        float yv[3][3];
#pragma unroll
        for (int r = 0; r < 3; ++r)
#pragma unroll
            for (int c = 0; c < 3; ++c)
                yv[r][c] = ysh[cin][i2 + r][j2 + c];
#pragma unroll
        for (int di = 0; di < 2; ++di)
#pragma unroll
            for (int rt = 0; rt < 2; ++rt) {
                const int row = di + rt;
                const int a   = 3 - di - 2 * rt;
#pragma unroll
                for (int dj = 0; dj < 2; ++dj)
#pragma unroll
                    for (int ct = 0; ct < 2; ++ct) {
                        const int col = dj + ct;
                        const int kb  = 3 - dj - 2 * ct;
                        const float vv = yv[row][col];
#pragma unroll
                        for (int o = 0; o < 9; ++o)
                            acc[di][dj][o] += vv * uw[cin * 144 + o * 16 + a * 4 + kb];
                    }
            }
    }

    // ---- epilogue: idwt2(LL1, LH, HL, HH) -> 4x4 output pixels / color ----
#pragma unroll
    for (int cc = 0; cc < 3; ++cc) {
#pragma unroll
        for (int di = 0; di < 2; ++di) {
            const int I = r0 + 2 * i2 + di;
            const int J = c0 + 2 * j2;
            const float2 llv = *reinterpret_cast<const float2*>(
                LL1 + (((size_t)b * 3 + cc) * 256 + I) * 256 + J);
            float4 top, bot;
            {
                const float ll = llv.x;
                const float lh = acc[di][0][cc * 3 + 0];
                const float hl = acc[di][0][cc * 3 + 1];
                const float hh = acc[di][0][cc * 3 + 2];
                const float e0 = ll + lh, od0 = ll - lh;
                const float e1 = hl + hh, od1 = hl - hh;
                top.x = (e0 + e1) * 0.5f; top.y = (e0 - e1) * 0.5f;
                bot.x = (od0 + od1) * 0.5f; bot.y = (od0 - od1) * 0.5f;
            }
            {
                const float ll = llv.y;
                const float lh = acc[di][1][cc * 3 + 0];
                const float hl = acc[di][1][cc * 3 + 1];
                const float hh = acc[di][1][cc * 3 + 2];
                const float e0 = ll + lh, od0 = ll - lh;
                const float e1 = hl + hh, od1 = hl - hh;
                top.z = (e0 + e1) * 0.5f; top.w = (e0 - e1) * 0.5f;
                bot.z = (od0 + od1) * 0.5f; bot.w = (od0 - od1) * 0.5f;
            }
            float* op = out + (((size_t)b * 3 + cc) * 512 + 2 * I) * 512 + 2 * J;
            *reinterpret_cast<float4*>(op) = top;
            *reinterpret_cast<float4*>(op + 512) = bot;
        }
    }
}

extern "C" void kernel_launch(void* const* d_in, const int* in_sizes, int n_in,
                              void* d_out, int out_size, void* d_ws, size_t ws_size,
                              hipStream_t stream) {
    const float* x  = (const float*)d_in[0];
    const float* dw = (const float*)d_in[1];
    const float* db = (const float*)d_in[2];
    const float* uw = (const float*)d_in[3];
    const float* ub = (const float*)d_in[4];
    float* outp = (float*)d_out;

    float* LL1 = (float*)d_ws;                                // 32*3*256*256 f32 = 25.2 MB
    float* y   = LL1 + (size_t)BB * 3 * 256 * 256;            // 32*9*128*128 f32 = 18.9 MB

    dim3 blk(256);
    k1_dwt_down<<<dim3(BB * 64), blk, 0, stream>>>(x, dw, db, LL1, y);
    k2_up_idwt<<<dim3(BB * 64), blk, 0, stream>>>(y, uw, ub, LL1, outp);
}